// Round 8
// baseline (5811.526 us; speedup 1.0000x reference)
//
#include <hip/hip_runtime.h>
#include <cstdint>
#include <cstddef>

typedef unsigned short u16;
typedef __attribute__((ext_vector_type(8))) short short8;
typedef __attribute__((ext_vector_type(4))) short short4v;
typedef __attribute__((ext_vector_type(4))) float f32x4;

#define NB 512
#define NT 64
#define ND 16
#define NH 1024

#define WAITV(N) asm volatile("s_waitcnt vmcnt(" #N ")" ::: "memory")

__device__ __forceinline__ u16 f2bf(float x) {
  union { float f; unsigned u; } v; v.f = x;
  unsigned r = v.u + 0x7fffu + ((v.u >> 16) & 1u);
  return (u16)(r >> 16);
}
__device__ __forceinline__ float bf2f(u16 u) {
  union { float f; unsigned u; } v; v.u = ((unsigned)u) << 16;
  return v.f;
}
__device__ __forceinline__ float sigf(float x) { return 1.f / (1.f + __expf(-x)); }

__device__ __forceinline__ void glds16(const void* g, void* l) {
  __builtin_amdgcn_global_load_lds((const __attribute__((address_space(1))) void*)g,
                                   (__attribute__((address_space(3))) void*)l, 16, 0, 0);
}

// XOR swizzle for h-state rows: 16B-slot ^= (row & 7) within each 64-col chunk.
__device__ __forceinline__ int swz(int row, int col) {
  return ((((col >> 3) ^ (row & 7)) << 3) | (col & 7));
}

// n' = (h/16)*64 + gate*16 + (h%16)  ->  orig row = gate*1024 + h
__device__ __forceinline__ int inv_np(int np) {
  int hb = np >> 6, g = (np >> 4) & 3, hlo = np & 15;
  return g * 1024 + hb * 16 + hlo;
}

// ---------------- prep: big weights -> bf16 fragment layout, COALESCED 16B/thread writes ----------------
// layout: [mat][nb(256)][kb(32)][lane(64)][8] ; lane = fq*16+fr ; np=nb*16+fr ; k=kb*32+fq*8+e
__global__ void k_prep_big(const float* s0, const float* s1, const float* s2,
                           const float* s3, const float* s4, const float* s5, u16* dst) {
  unsigned q = blockIdx.x * 256 + threadIdx.x;   // 12288*256 = 3145728 slots exact
  int mat = q >> 19;
  int r = q & ((1 << 19) - 1);
  int nb = r >> 11, kb = (r >> 6) & 31, l = r & 63;
  int fr = l & 15, fq = l >> 4;
  int np = nb * 16 + fr;
  int row = inv_np(np);
  int k0 = kb * 32 + fq * 8;
  const float* s = mat == 0 ? s0 : mat == 1 ? s1 : mat == 2 ? s2 : mat == 3 ? s3 : mat == 4 ? s4 : s5;
  const float* sr = s + (size_t)row * NH + k0;
  float4 v0 = *(const float4*)sr;
  float4 v1 = *(const float4*)(sr + 4);
  short8 o;
  o[0] = (short)f2bf(v0.x); o[1] = (short)f2bf(v0.y); o[2] = (short)f2bf(v0.z); o[3] = (short)f2bf(v0.w);
  o[4] = (short)f2bf(v1.x); o[5] = (short)f2bf(v1.y); o[6] = (short)f2bf(v1.z); o[7] = (short)f2bf(v1.w);
  *(short8*)(dst + (size_t)q * 8) = o;
}

// ---------------- prep: Wih0 fragment layout (K padded to 64), biases, out_W bf16 ----------------
__global__ void k_prep_small(const float* fwih0, const float* bwih0,
                             const float* fbi0, const float* fbh0, const float* fbi1, const float* fbh1,
                             const float* bbi0, const float* bbh0, const float* bbi1, const float* bbh1,
                             const float* outW,
                             u16* wih0p, float* biasb, u16* owbf) {
  int idx = blockIdx.x * 256 + threadIdx.x;
  if (idx < 524288) {
    int dir = idx >> 18;
    int r = idx & 262143;
    int np = r >> 6, d = r & 63;
    int row = inv_np(np);
    const float* s = dir ? bwih0 : fwih0;
    float v = (d < 16) ? s[row * 16 + d] : 0.f;
    int nb = np >> 4, fr = np & 15, kb = d >> 5, fq = (d >> 3) & 3, e = d & 7;
    wih0p[(size_t)dir * 262144 + (size_t)((nb * 2 + kb) * 64 + fq * 16 + fr) * 8 + e] = f2bf(v);
  } else if (idx < 524288 + 16384) {
    int j = idx - 524288;
    int which = j >> 12;
    int np = j & 4095;
    int row = inv_np(np);
    const float* bi = which == 0 ? fbi0 : which == 1 ? fbi1 : which == 2 ? bbi0 : bbi1;
    const float* bh = which == 0 ? fbh0 : which == 1 ? fbh1 : which == 2 ? bbh0 : bbh1;
    biasb[which * 4096 + np] = bi[row] + bh[row];
  } else if (idx < 524288 + 16384 + 16384) {
    int j = idx - 524288 - 16384;
    owbf[j] = f2bf(outW[j]);
  }
}

__global__ void k_init(const float* fbi1, const float* fbh1, const float* bbi1, const float* bbh1,
                       float* c0, float* c1, u16* h0bf, u16* h1bf) {
  int idx = blockIdx.x * 256 + threadIdx.x;
  int dir = idx >> 19;
  int rem = idx & ((1 << 19) - 1);
  int b = rem >> 10, h = rem & 1023;
  const float* bi = dir ? bbi1 : fbi1;
  const float* bh = dir ? bbh1 : fbh1;
  float gi = bi[h] + bh[h];
  float gg = bi[2048 + h] + bh[2048 + h];
  float go = bi[3072 + h] + bh[3072 + h];
  float c = sigf(gi) * tanhf(gg);
  float hv = sigf(go) * tanhf(c);
  size_t o = (size_t)dir * 524288 + rem;
  c1[o] = c;
  h1bf[(size_t)(dir * 2) * 524288 + (size_t)b * NH + swz(b, h)] = f2bf(hv);
  c0[o] = 0.f;
  h0bf[(size_t)(dir * 2) * 524288 + rem] = 0;
}

// t=0 cc seed -> slice 0; other 63 slices zeroed by memset
__global__ __launch_bounds__(256) void k_cc0(const u16* h1f, const u16* h1b,
                                             const float* outW, float* partial) {
  int dir = blockIdx.y;
  int w = threadIdx.x >> 6, lane = threadIdx.x & 63;
  int b = blockIdx.x * 4 + w;
  const u16* hb = dir ? h1b : h1f;
  int key = b & 7;
  short8 ha = *(const short8*)(hb + (size_t)b * NH + ((lane * 2) ^ key) * 8);
  short8 hc = *(const short8*)(hb + (size_t)b * NH + ((lane * 2 + 1) ^ key) * 8);
  float hf[16];
#pragma unroll
  for (int j = 0; j < 8; ++j) { hf[j] = bf2f((u16)ha[j]); hf[8 + j] = bf2f((u16)hc[j]); }
  float sums[16];
#pragma unroll
  for (int d = 0; d < 16; ++d) {
    const float* wr = outW + (size_t)d * NH + lane * 16;
    float s = 0.f;
#pragma unroll
    for (int j = 0; j < 16; ++j) s += hf[j] * wr[j];
#pragma unroll
    for (int off = 32; off; off >>= 1) s += __shfl_xor(s, off);
    sums[d] = s;
  }
  if (lane == 0) {
    float* dst = partial + (size_t)dir * 524288 + (size_t)b * 16;
#pragma unroll
    for (int d = 0; d < 16; ++d) dst[d] = sums[d];
  }
}

// ================= fragment machinery =================
struct BF { short8 b[8]; };

struct StepCtx {
  u16* h0bf; u16* h1bf;
  const u16* wbig; const u16* wih0p;
  const float* biasb;
  float* c0; float* c1;
  float* partial;                 // [dir][64 slices][512][16] f32
  const float* values; const float* masks; const float* outb;
  const u16* owbf;
};

// ================= g0: gates = cc@Wih0^T + h0@Whh0^T ; LSTM cell =================
__global__ __launch_bounds__(256, 2) void k_g0(StepCtx a, int t) {
  __shared__ u16 SM[5 * 4096];    // 4 A-buffers (8KB each) + cc scratch
  const int dir = blockIdx.z, m_blk = blockIdx.y, n_blk = blockIdx.x;
  const int p = t & 1;
  const int m0 = m_blk * 64, n0 = n_blk * 128;
  const int tid = threadIdx.x, w = tid >> 6, lane = tid & 63;
  const int srow = lane >> 3, scol = (lane & 7) * 8;
  const int wm = w >> 1, wn = w & 1;
  const int fr = lane & 15, fq = lane >> 4, key = fr & 7;
  const int lane8 = lane * 8;
  const int nbb = n_blk * 8 + wn * 4;
  const u16* h0_in = a.h0bf + (size_t)(dir * 2 + p) * 524288;
  u16* h0_out = a.h0bf + (size_t)(dir * 2 + 1 - p) * 524288;
  const u16* W00 = a.wbig + (size_t)(dir * 3 + 0) * 4194304;
  const u16* Wcc = a.wih0p + (size_t)dir * 262144;
  const float* bias0 = a.biasb + (size_t)dir * 2 * 4096;
  float* cs0 = a.c0 + (size_t)dir * 524288;

  int aoff[4];
#pragma unroll
  for (int mi = 0; mi < 2; ++mi)
#pragma unroll
    for (int kk = 0; kk < 2; ++kk)
      aoff[mi * 2 + kk] = (wm * 32 + mi * 16 + fr) * 64 + ((fq + kk * 4) ^ key) * 8;

  f32x4 acc[2][4];
#pragma unroll
  for (int i = 0; i < 2; ++i)
#pragma unroll
    for (int j = 0; j < 4; ++j) acc[i][j] = f32x4{0.f, 0.f, 0.f, 0.f};

  auto stageA = [&](int c) {               // chunks 1..16: A = h0_in cols (c-1)*64
    u16* lb = SM + (c & 3) * 4096;
    const u16* pa = h0_in + (size_t)(c - 1) * 64;
    glds16(pa + (size_t)(m0 + w * 16 + srow) * NH + scol, lb + (w * 16) * 64);
    glds16(pa + (size_t)(m0 + w * 16 + 8 + srow) * NH + scol, lb + (w * 16 + 8) * 64);
  };
  auto LDB = [&](int c, BF& F) {           // chunks 1..16: B = W00 kb-pair (c-1)
    int ci = c - 1;
#pragma unroll
    for (int ni = 0; ni < 4; ++ni)
#pragma unroll
      for (int kk = 0; kk < 2; ++kk)
        F.b[ni * 2 + kk] = *(const short8*)(W00 + (size_t)((nbb + ni) * 32 + ci * 2 + kk) * 512 + lane8);
  };
  auto domfma = [&](const short8 (&af)[4], const BF& B) {
#pragma unroll
    for (int kk = 0; kk < 2; ++kk)
#pragma unroll
      for (int mi = 0; mi < 2; ++mi)
#pragma unroll
        for (int ni = 0; ni < 4; ++ni)
          acc[mi][ni] = __builtin_amdgcn_mfma_f32_16x16x32_bf16(af[mi * 2 + kk], B.b[ni * 2 + kk],
                                                                acc[mi][ni], 0, 0, 0);
  };
  auto DO = [&](int x, BF& B, int st, int lb) {
    __builtin_amdgcn_s_barrier();
    __builtin_amdgcn_sched_barrier(0);
    if (st >= 0) stageA(st);
    short8 af[4];
    const u16* base = SM + (x & 3) * 4096;
#pragma unroll
    for (int i = 0; i < 4; ++i) af[i] = *(const short8*)(base + aoff[i]);
    domfma(af, B);
    if (lb >= 0) LDB(lb, B);
  };

  BF Ba, Bb, Bc;
  // preamble: B(0)=Wcc frags, A(1..3) staged, B(1),B(2)
#pragma unroll
  for (int ni = 0; ni < 4; ++ni)
#pragma unroll
    for (int kk = 0; kk < 2; ++kk)
      Ba.b[ni * 2 + kk] = *(const short8*)(Wcc + (size_t)((nbb + ni) * 2 + kk) * 512 + lane8);
  stageA(1); stageA(2); stageA(3);
  LDB(1, Bb); LDB(2, Bc);

  // prologue: reduce 64 cc partial slices, apply mask, write cc tile (swizzled) to SM scratch
  {
    u16* SM4 = SM + 4 * 4096;
    const int rl = tid >> 2, q = tid & 3;
    const int grow = m0 + rl;
    const int d4 = q * 4;
    float4 ps0 = {0.f, 0.f, 0.f, 0.f}, ps1 = {0.f, 0.f, 0.f, 0.f};
    const float* pp = a.partial + (size_t)dir * 524288 + (size_t)grow * 16 + d4;
#pragma unroll 4
    for (int nb = 0; nb < 64; nb += 2) {
      float4 v0 = *(const float4*)(pp + (size_t)nb * 8192);
      float4 v1 = *(const float4*)(pp + (size_t)(nb + 1) * 8192);
      ps0.x += v0.x; ps0.y += v0.y; ps0.z += v0.z; ps0.w += v0.w;
      ps1.x += v1.x; ps1.y += v1.y; ps1.z += v1.z; ps1.w += v1.w;
    }
    float4 ps = {ps0.x + ps1.x, ps0.y + ps1.y, ps0.z + ps1.z, ps0.w + ps1.w};
    int tt = dir ? (NT - 1 - t) : t;
    float4 x = *(const float4*)(a.values + ((size_t)grow * NT + tt) * ND + d4);
    float4 m = *(const float4*)(a.masks + ((size_t)grow * NT + tt) * ND + d4);
    float4 ob = *(const float4*)(a.outb + d4);
    short4v cc;
    cc[0] = (short)f2bf((1.f - m.x) * (ps.x + ob.x) + m.x * x.x);
    cc[1] = (short)f2bf((1.f - m.y) * (ps.y + ob.y) + m.y * x.y);
    cc[2] = (short)f2bf((1.f - m.z) * (ps.z + ob.z) + m.z * x.z);
    cc[3] = (short)f2bf((1.f - m.w) * (ps.w + ob.w) + m.w * x.w);
    int k2 = rl & 7;
    *(short4v*)(SM4 + rl * 64 + (((d4 >> 3) ^ k2) << 3) + (d4 & 7)) = cc;
    short8 z8 = {0, 0, 0, 0, 0, 0, 0, 0};
    *(short8*)(SM4 + rl * 64 + (((2 + q) ^ k2) << 3)) = z8;
    if (q < 2) *(short8*)(SM4 + rl * 64 + (((6 + q) ^ k2) << 3)) = z8;
    asm volatile("s_waitcnt lgkmcnt(0)" ::: "memory");
    __builtin_amdgcn_sched_barrier(0);
  }

  // chunk 0: A from SM scratch, B = Ba (Wcc)
  __builtin_amdgcn_s_barrier();
  __builtin_amdgcn_sched_barrier(0);
  {
    short8 af[4];
    const u16* SM4 = SM + 4 * 4096;
#pragma unroll
    for (int i = 0; i < 4; ++i) af[i] = *(const short8*)(SM4 + aoff[i]);
    domfma(af, Ba);
    LDB(3, Ba);
  }
  // main: chunks 1..12
  for (int c = 1; c < 13; c += 3) {
    WAITV(28); DO(c, Bb, c + 3, c + 3);
    WAITV(28); DO(c + 1, Bc, c + 4, c + 4);
    WAITV(28); DO(c + 2, Ba, c + 5, c + 5);
  }
  // tail: 13..16
  WAITV(28); DO(13, Bb, 16, 16);
  WAITV(28); DO(14, Bc, -1, -1);
  WAITV(18); DO(15, Ba, -1, -1);
  WAITV(8);  DO(16, Bb, -1, -1);

  const int hg = ((n0 + wn * 64) >> 2) + fr;
  const float b0 = bias0[n0 + wn * 64 + fr];
  const float b1 = bias0[n0 + wn * 64 + 16 + fr];
  const float b2 = bias0[n0 + wn * 64 + 32 + fr];
  const float b3 = bias0[n0 + wn * 64 + 48 + fr];
#pragma unroll
  for (int mi = 0; mi < 2; ++mi)
#pragma unroll
    for (int r = 0; r < 4; ++r) {
      int row = m0 + wm * 32 + mi * 16 + fq * 4 + r;
      size_t sidx = (size_t)row * NH + hg;
      float iv = acc[mi][0][r] + b0;
      float fv = acc[mi][1][r] + b1;
      float gv = acc[mi][2][r] + b2;
      float ov = acc[mi][3][r] + b3;
      float cp = cs0[sidx];
      float c2 = sigf(fv) * cp + sigf(iv) * tanhf(gv);
      float hvv = sigf(ov) * tanhf(c2);
      cs0[sidx] = c2;
      h0_out[(size_t)row * NH + swz(row, hg)] = f2bf(hvv);
    }
}

// ================= g1: gates = h0@Wih1^T + h1@Whh1^T ; cell + cc-partial =================
__global__ __launch_bounds__(256, 2) void k_g1(StepCtx a, int t) {
  __shared__ u16 SM[4 * 4096];
  const int dir = blockIdx.z, m_blk = blockIdx.y, n_blk = blockIdx.x;
  const int p = t & 1;
  const int m0 = m_blk * 64, n0 = n_blk * 128;
  const int tid = threadIdx.x, w = tid >> 6, lane = tid & 63;
  const int srow = lane >> 3, scol = (lane & 7) * 8;
  const int wm = w >> 1, wn = w & 1;
  const int fr = lane & 15, fq = lane >> 4, key = fr & 7;
  const int lane8 = lane * 8;
  const int nbb = n_blk * 8 + wn * 4;
  const u16* h0_new = a.h0bf + (size_t)(dir * 2 + 1 - p) * 524288;
  const u16* h1_in = a.h1bf + (size_t)(dir * 2 + p) * 524288;
  u16* h1_out = a.h1bf + (size_t)(dir * 2 + 1 - p) * 524288;
  const u16* W10 = a.wbig + (size_t)(dir * 3 + 1) * 4194304;
  const u16* W11 = a.wbig + (size_t)(dir * 3 + 2) * 4194304;
  const float* bias1 = a.biasb + (size_t)(dir * 2 + 1) * 4096;
  float* cs1 = a.c1 + (size_t)dir * 524288;

  int aoff[4];
#pragma unroll
  for (int mi = 0; mi < 2; ++mi)
#pragma unroll
    for (int kk = 0; kk < 2; ++kk)
      aoff[mi * 2 + kk] = (wm * 32 + mi * 16 + fr) * 64 + ((fq + kk * 4) ^ key) * 8;

  f32x4 acc[2][4];
#pragma unroll
  for (int i = 0; i < 2; ++i)
#pragma unroll
    for (int j = 0; j < 4; ++j) acc[i][j] = f32x4{0.f, 0.f, 0.f, 0.f};

  auto stageA = [&](int c) {
    u16* lb = SM + (c & 3) * 4096;
    const u16* pa = (c < 16) ? (h0_new + (size_t)c * 64) : (h1_in + (size_t)(c - 16) * 64);
    glds16(pa + (size_t)(m0 + w * 16 + srow) * NH + scol, lb + (w * 16) * 64);
    glds16(pa + (size_t)(m0 + w * 16 + 8 + srow) * NH + scol, lb + (w * 16 + 8) * 64);
  };
  auto LDB = [&](int c, BF& F) {
    const u16* wb = (c < 16) ? W10 : W11;
    int ci = (c < 16) ? c : c - 16;
#pragma unroll
    for (int ni = 0; ni < 4; ++ni)
#pragma unroll
      for (int kk = 0; kk < 2; ++kk)
        F.b[ni * 2 + kk] = *(const short8*)(wb + (size_t)((nbb + ni) * 32 + ci * 2 + kk) * 512 + lane8);
  };
  auto domfma = [&](const short8 (&af)[4], const BF& B) {
#pragma unroll
    for (int kk = 0; kk < 2; ++kk)
#pragma unroll
      for (int mi = 0; mi < 2; ++mi)
#pragma unroll
        for (int ni = 0; ni < 4; ++ni)
          acc[mi][ni] = __builtin_amdgcn_mfma_f32_16x16x32_bf16(af[mi * 2 + kk], B.b[ni * 2 + kk],
                                                                acc[mi][ni], 0, 0, 0);
  };
  auto DO = [&](int x, BF& B, int st, int lb) {
    __builtin_amdgcn_s_barrier();
    __builtin_amdgcn_sched_barrier(0);
    if (st >= 0) stageA(st);
    short8 af[4];
    const u16* base = SM + (x & 3) * 4096;
#pragma unroll
    for (int i = 0; i < 4; ++i) af[i] = *(const short8*)(base + aoff[i]);
    domfma(af, B);
    if (lb >= 0) LDB(lb, B);
  };

  BF Ba, Bb, Bc;
  stageA(0); stageA(1); stageA(2);
  LDB(0, Ba); LDB(1, Bb); LDB(2, Bc);

  // main: chunks 0..26
  for (int c = 0; c < 27; c += 3) {
    WAITV(28); DO(c, Ba, c + 3, c + 3);
    WAITV(28); DO(c + 1, Bb, c + 4, c + 4);
    WAITV(28); DO(c + 2, Bc, c + 5, c + 5);
  }
  // tail: 27..31
  WAITV(28); DO(27, Ba, 30, 30);
  WAITV(28); DO(28, Bb, 31, 31);
  WAITV(28); DO(29, Bc, -1, -1);
  WAITV(18); DO(30, Ba, -1, -1);
  WAITV(8);  DO(31, Bb, -1, -1);

  const int hb4 = (n0 + wn * 64) >> 2;
  const int hg = hb4 + fr;
  const float b0 = bias1[n0 + wn * 64 + fr];
  const float b1 = bias1[n0 + wn * 64 + 16 + fr];
  const float b2 = bias1[n0 + wn * 64 + 32 + fr];
  const float b3 = bias1[n0 + wn * 64 + 48 + fr];
  float hsv[2][4];
#pragma unroll
  for (int mi = 0; mi < 2; ++mi)
#pragma unroll
    for (int r = 0; r < 4; ++r) {
      int row = m0 + wm * 32 + mi * 16 + fq * 4 + r;
      size_t sidx = (size_t)row * NH + hg;
      float iv = acc[mi][0][r] + b0;
      float fv = acc[mi][1][r] + b1;
      float gv = acc[mi][2][r] + b2;
      float ov = acc[mi][3][r] + b3;
      float cp = cs1[sidx];
      float c2 = sigf(fv) * cp + sigf(iv) * tanhf(gv);
      float hvv = sigf(ov) * tanhf(c2);
      cs1[sidx] = c2;
      h1_out[(size_t)row * NH + swz(row, hg)] = f2bf(hvv);
      hsv[mi][r] = hvv;
    }

  // partial cc = h1_tile @ outW^T via transpose-MFMA; per (n_blk, wn) slice
  {
    u16* ts = SM + w * 512;  // per-wave 16x32 scratch (all buffers retired)
    *(short4v*)(ts + (lane >> 2) * 32 + 16 + (lane & 3) * 4) = short4v{0, 0, 0, 0};
    short8 afr = {0, 0, 0, 0, 0, 0, 0, 0};
    if (fq < 2) afr = *(const short8*)(a.owbf + (size_t)fr * NH + hb4 + fq * 8);
    float* pout = a.partial + ((size_t)(dir * 64 + n_blk * 2 + wn) * 512) * 16;
#pragma unroll
    for (int mi = 0; mi < 2; ++mi) {
#pragma unroll
      for (int r = 0; r < 4; ++r)
        *(ts + (fq * 4 + r) * 32 + fr) = f2bf(hsv[mi][r]);
      asm volatile("s_waitcnt lgkmcnt(0)" ::: "memory");
      __builtin_amdgcn_sched_barrier(0);
      short8 bfr2 = *(const short8*)(ts + fr * 32 + fq * 8);
      f32x4 pz = {0.f, 0.f, 0.f, 0.f};
      pz = __builtin_amdgcn_mfma_f32_16x16x32_bf16(afr, bfr2, pz, 0, 0, 0);
      int row = m0 + wm * 32 + mi * 16 + fr;
      float4 st = {pz[0], pz[1], pz[2], pz[3]};
      *(float4*)(pout + (size_t)row * 16 + fq * 4) = st;
      asm volatile("s_waitcnt lgkmcnt(0)" ::: "memory");
      __builtin_amdgcn_sched_barrier(0);
    }
  }
}

// ---------------- final outputs ----------------
__global__ void k_final(const u16* hf1, const u16* hb1, const float* values,
                        const float* masks, float* out) {
  int idx = blockIdx.x * 256 + threadIdx.x;
  int b = idx >> 10, j = idx & 1023;
  float hf = bf2f(hf1[(size_t)b * NH + swz(b, j)]);
  int jr = NH - 1 - j;
  float hb = bf2f(hb1[(size_t)b * NH + swz(b, jr)]);
  float hv = 0.5f * (hf + hb);
  float m = masks[idx];
  out[idx] = hv;
  out[524288 + idx] = hv;
  out[1048576 + idx] = hv * (1.f - m) + values[idx] * m;
}

extern "C" void kernel_launch(void* const* d_in, const int* in_sizes, int n_in,
                              void* d_out, int out_size, void* d_ws, size_t ws_size,
                              hipStream_t stream) {
  const float* values  = (const float*)d_in[0];
  const float* masks   = (const float*)d_in[1];
  const float* fw_Wih0 = (const float*)d_in[2];
  const float* fw_Whh0 = (const float*)d_in[3];
  const float* fw_bih0 = (const float*)d_in[4];
  const float* fw_bhh0 = (const float*)d_in[5];
  const float* fw_Wih1 = (const float*)d_in[6];
  const float* fw_Whh1 = (const float*)d_in[7];
  const float* fw_bih1 = (const float*)d_in[8];
  const float* fw_bhh1 = (const float*)d_in[9];
  const float* bw_Wih0 = (const float*)d_in[10];
  const float* bw_Whh0 = (const float*)d_in[11];
  const float* bw_bih0 = (const float*)d_in[12];
  const float* bw_bhh0 = (const float*)d_in[13];
  const float* bw_Wih1 = (const float*)d_in[14];
  const float* bw_Whh1 = (const float*)d_in[15];
  const float* bw_bih1 = (const float*)d_in[16];
  const float* bw_bhh1 = (const float*)d_in[17];
  const float* out_W   = (const float*)d_in[18];
  const float* out_b   = (const float*)d_in[19];

  char* ws = (char*)d_ws;
  u16* wbig    = (u16*)ws;                    // 6 x 4M u16 (fragment layout)
  u16* wih0p   = (u16*)(ws + 50331648);       // 2 x 4096x64 (fragment layout)
  float* biasb = (float*)(ws + 51380224);     // 4 x 4096
  u16* owbf    = (u16*)(ws + 51445760);       // 16x1024 bf16
  float* c0    = (float*)(ws + 51478528);     // 2 x 512x1024 f32
  float* c1    = (float*)(ws + 55672832);
  u16* h0bf    = (u16*)(ws + 59867136);       // [dir][pp] x 512x1024 bf16 swizzled
  u16* h1bf    = (u16*)(ws + 64061440);
  float* partial = (float*)(ws + 68255744);   // [dir][64][512][16] f32 = 4 MB
  if (ws_size < 72450048) return;

  k_prep_big<<<12288, 256, 0, stream>>>(fw_Whh0, fw_Wih1, fw_Whh1, bw_Whh0, bw_Wih1, bw_Whh1, wbig);
  k_prep_small<<<2176, 256, 0, stream>>>(fw_Wih0, bw_Wih0, fw_bih0, fw_bhh0, fw_bih1, fw_bhh1,
                                         bw_bih0, bw_bhh0, bw_bih1, bw_bhh1, out_W,
                                         wih0p, biasb, owbf);
  k_init<<<4096, 256, 0, stream>>>(fw_bih1, fw_bhh1, bw_bih1, bw_bhh1, c0, c1, h0bf, h1bf);
  hipMemsetAsync(partial, 0, 4194304, stream);
  k_cc0<<<dim3(128, 2), 256, 0, stream>>>(h1bf, h1bf + (size_t)2 * 524288, out_W, partial);

  StepCtx sc;
  sc.h0bf = h0bf; sc.h1bf = h1bf;
  sc.wbig = wbig; sc.wih0p = wih0p;
  sc.biasb = biasb; sc.c0 = c0; sc.c1 = c1;
  sc.partial = partial;
  sc.values = values; sc.masks = masks; sc.outb = out_b;
  sc.owbf = owbf;

  for (int t = 0; t < NT; ++t) {
    k_g0<<<dim3(32, 8, 2), 256, 0, stream>>>(sc, t);
    k_g1<<<dim3(32, 8, 2), 256, 0, stream>>>(sc, t);
  }

  // after t=63: p=1, final h1 in buffer (1-p)=0
  k_final<<<2048, 256, 0, stream>>>(h1bf, h1bf + (size_t)2 * 524288, values, masks, (float*)d_out);
}

// Round 9
// 3268.172 us; speedup vs baseline: 1.7782x; 1.7782x over previous
//
#include <hip/hip_runtime.h>
#include <cstdint>
#include <cstddef>

typedef unsigned short u16;
typedef __attribute__((ext_vector_type(8))) short short8;
typedef __attribute__((ext_vector_type(4))) short short4v;
typedef __attribute__((ext_vector_type(4))) float f32x4;

#define NB 512
#define NT 64
#define ND 16
#define NH 1024

#define WAITV(N) asm volatile("s_waitcnt vmcnt(" #N ")" ::: "memory")
#define BARR __builtin_amdgcn_s_barrier(); __builtin_amdgcn_sched_barrier(0)

__device__ __forceinline__ u16 f2bf(float x) {
  union { float f; unsigned u; } v; v.f = x;
  unsigned r = v.u + 0x7fffu + ((v.u >> 16) & 1u);
  return (u16)(r >> 16);
}
__device__ __forceinline__ float bf2f(u16 u) {
  union { float f; unsigned u; } v; v.u = ((unsigned)u) << 16;
  return v.f;
}
__device__ __forceinline__ float sigf(float x) { return 1.f / (1.f + __expf(-x)); }

__device__ __forceinline__ void glds16(const void* g, void* l) {
  __builtin_amdgcn_global_load_lds((const __attribute__((address_space(1))) void*)g,
                                   (__attribute__((address_space(3))) void*)l, 16, 0, 0);
}

// XOR swizzle: 16B-slot ^= (row & 7) within each 64-col chunk.
__device__ __forceinline__ int swz(int row, int col) {
  return ((((col >> 3) ^ (row & 7)) << 3) | (col & 7));
}

// n' = (h/16)*64 + gate*16 + (h%16)  ->  orig row = gate*1024 + h
__device__ __forceinline__ int inv_np(int np) {
  int hb = np >> 6, g = (np >> 4) & 3, hlo = np & 15;
  return g * 1024 + hb * 16 + hlo;
}

// ---------------- prep kernels (R6-proven) ----------------
__global__ void k_prep_big(const float* s0, const float* s1, const float* s2,
                           const float* s3, const float* s4, const float* s5, u16* dst) {
  for (unsigned q = blockIdx.x * 256 + threadIdx.x; q < (6u << 20); q += gridDim.x * 256) {
    int mat = q >> 20;
    int rem = q & ((1 << 20) - 1);
    int np = rem >> 8;
    int k = (rem & 255) * 4;
    int row = inv_np(np);
    const float* s = mat == 0 ? s0 : mat == 1 ? s1 : mat == 2 ? s2 : mat == 3 ? s3 : mat == 4 ? s4 : s5;
    float4 v = *(const float4*)(s + (size_t)row * NH + k);
    u16* d = dst + (size_t)mat * 4194304 + (size_t)np * NH + swz(np, k);
    d[0] = f2bf(v.x); d[1] = f2bf(v.y); d[2] = f2bf(v.z); d[3] = f2bf(v.w);
  }
}

__global__ void k_prep_small(const float* fwih0, const float* bwih0,
                             const float* fbi0, const float* fbh0, const float* fbi1, const float* fbh1,
                             const float* bbi0, const float* bbh0, const float* bbi1, const float* bbh1,
                             const float* outW,
                             u16* wih0p, float* biasb, u16* owbf) {
  int idx = blockIdx.x * 256 + threadIdx.x;
  if (idx < 524288) {
    int dir = idx >> 18;
    int r = idx & 262143;
    int np = r >> 6, d = r & 63;
    int row = inv_np(np);
    const float* s = dir ? bwih0 : fwih0;
    float v = (d < 16) ? s[row * 16 + d] : 0.f;
    wih0p[(size_t)dir * 262144 + (size_t)np * 64 + swz(np, d)] = f2bf(v);
  } else if (idx < 524288 + 16384) {
    int j = idx - 524288;
    int which = j >> 12;
    int np = j & 4095;
    int row = inv_np(np);
    const float* bi = which == 0 ? fbi0 : which == 1 ? fbi1 : which == 2 ? bbi0 : bbi1;
    const float* bh = which == 0 ? fbh0 : which == 1 ? fbh1 : which == 2 ? bbh0 : bbh1;
    biasb[which * 4096 + np] = bi[row] + bh[row];
  } else if (idx < 524288 + 16384 + 16384) {
    int j = idx - 524288 - 16384;
    owbf[j] = f2bf(outW[j]);
  }
}

__global__ void k_init(const float* fbi1, const float* fbh1, const float* bbi1, const float* bbh1,
                       float* c0, float* c1, u16* h0bf, u16* h1bf) {
  int idx = blockIdx.x * 256 + threadIdx.x;
  int dir = idx >> 19;
  int rem = idx & ((1 << 19) - 1);
  int b = rem >> 10, h = rem & 1023;
  const float* bi = dir ? bbi1 : fbi1;
  const float* bh = dir ? bbh1 : fbh1;
  float gi = bi[h] + bh[h];
  float gg = bi[2048 + h] + bh[2048 + h];
  float go = bi[3072 + h] + bh[3072 + h];
  float c = sigf(gi) * tanhf(gg);
  float hv = sigf(go) * tanhf(c);
  size_t o = (size_t)dir * 524288 + rem;
  c1[o] = c;
  h1bf[(size_t)(dir * 2) * 524288 + (size_t)b * NH + swz(b, h)] = f2bf(hv);
  c0[o] = 0.f;
  h0bf[(size_t)(dir * 2) * 524288 + rem] = 0;
}

// t=0 cc seed -> slice 0; other 63 slices zeroed by memset
__global__ __launch_bounds__(256) void k_cc0(const u16* h1f, const u16* h1b,
                                             const float* outW, float* partial) {
  int dir = blockIdx.y;
  int w = threadIdx.x >> 6, lane = threadIdx.x & 63;
  int b = blockIdx.x * 4 + w;
  const u16* hb = dir ? h1b : h1f;
  int key = b & 7;
  short8 ha = *(const short8*)(hb + (size_t)b * NH + ((lane * 2) ^ key) * 8);
  short8 hc = *(const short8*)(hb + (size_t)b * NH + ((lane * 2 + 1) ^ key) * 8);
  float hf[16];
#pragma unroll
  for (int j = 0; j < 8; ++j) { hf[j] = bf2f((u16)ha[j]); hf[8 + j] = bf2f((u16)hc[j]); }
  float sums[16];
#pragma unroll
  for (int d = 0; d < 16; ++d) {
    const float* wr = outW + (size_t)d * NH + lane * 16;
    float s = 0.f;
#pragma unroll
    for (int j = 0; j < 16; ++j) s += hf[j] * wr[j];
#pragma unroll
    for (int off = 32; off; off >>= 1) s += __shfl_xor(s, off);
    sums[d] = s;
  }
  if (lane == 0) {
    float* dst = partial + (size_t)dir * 524288 + (size_t)b * 16;
#pragma unroll
    for (int d = 0; d < 16; ++d) dst[d] = sums[d];
  }
}

// ================= fragment machinery =================
struct AF { short8 a[4]; };

struct StepCtx {
  u16* h0bf; u16* h1bf;
  const u16* wbig; const u16* wih0p;
  const float* biasb;
  float* c0; float* c1;
  float* partial;                 // [dir][64 slices][512][16] f32
  const float* values; const float* masks; const float* outb;
  const u16* owbf;
};

// ================= g0: gates = cc@Wih0^T + h0@Whh0^T ; LSTM cell =================
__global__ __launch_bounds__(256, 2) void k_g0(StepCtx a, int t) {
  __shared__ u16 SM[3 * 8192 + 4096];   // 3 B-buffers (16 KB) + cc scratch (8 KB)
  const int dir = blockIdx.z, m_blk = blockIdx.y, n_blk = blockIdx.x;
  const int p = t & 1;
  const int m0 = m_blk * 64, n0 = n_blk * 128;
  const int tid = threadIdx.x, w = tid >> 6, lane = tid & 63;
  const int srow = lane >> 3, scol = (lane & 7) * 8;
  const int wm = w >> 1, wn = w & 1;
  const int fr = lane & 15, fq = lane >> 4, key = fr & 7;
  const u16* h0_in = a.h0bf + (size_t)(dir * 2 + p) * 524288;
  u16* h0_out = a.h0bf + (size_t)(dir * 2 + 1 - p) * 524288;
  const u16* W00 = a.wbig + (size_t)(dir * 3 + 0) * 4194304;
  const u16* Wcc = a.wih0p + (size_t)dir * 262144;
  const float* bias0 = a.biasb + (size_t)dir * 2 * 4096;
  float* cs0 = a.c0 + (size_t)dir * 524288;
  const u16* hA = h0_in + (size_t)m0 * NH;
  u16* SMX = SM + 3 * 8192;

  int aoffg[4], aoffs[4], boff[8];
#pragma unroll
  for (int mi = 0; mi < 2; ++mi)
#pragma unroll
    for (int kk = 0; kk < 2; ++kk) {
      aoffg[mi * 2 + kk] = (wm * 32 + mi * 16 + fr) * NH + ((fq + kk * 4) ^ key) * 8;
      aoffs[mi * 2 + kk] = (wm * 32 + mi * 16 + fr) * 64 + ((fq + kk * 4) ^ key) * 8;
    }
#pragma unroll
  for (int ni = 0; ni < 4; ++ni)
#pragma unroll
    for (int kk = 0; kk < 2; ++kk)
      boff[ni * 2 + kk] = (wn * 64 + ni * 16 + fr) * 64 + ((fq + kk * 4) ^ key) * 8;

  f32x4 acc[2][4];
#pragma unroll
  for (int i = 0; i < 2; ++i)
#pragma unroll
    for (int j = 0; j < 4; ++j) acc[i][j] = f32x4{0.f, 0.f, 0.f, 0.f};

  auto stageB = [&](int c, int buf) {     // chunks 1..16: B = W00 cols (c-1)*64
    u16* lb = SM + buf * 8192;
    const u16* pw = W00 + (size_t)(c - 1) * 64;
#pragma unroll
    for (int k = 0; k < 4; ++k)
      glds16(pw + (size_t)(n0 + w * 32 + k * 8 + srow) * NH + scol, lb + (w * 32 + k * 8) * 64);
  };
  auto ldA = [&](int c, AF& F) {
    const u16* pa = hA + (size_t)(c - 1) * 64;
#pragma unroll
    for (int i = 0; i < 4; ++i) F.a[i] = *(const short8*)(pa + aoffg[i]);
  };
  auto comp = [&](int buf, const AF& F) {
    const u16* base = SM + buf * 8192;
#pragma unroll
    for (int ni = 0; ni < 4; ++ni)
#pragma unroll
      for (int kk = 0; kk < 2; ++kk) {
        short8 bfrag = *(const short8*)(base + boff[ni * 2 + kk]);
#pragma unroll
        for (int mi = 0; mi < 2; ++mi)
          acc[mi][ni] = __builtin_amdgcn_mfma_f32_16x16x32_bf16(F.a[mi * 2 + kk], bfrag, acc[mi][ni], 0, 0, 0);
      }
  };

  AF Aa, Ab, Ac;
  // preamble: Wcc -> buf0 (4 glds), chunk1 staged (4 glds + 4 A-loads)
#pragma unroll
  for (int k = 0; k < 4; ++k)
    glds16(Wcc + (size_t)(n0 + w * 32 + k * 8 + srow) * 64 + scol, SM + (w * 32 + k * 8) * 64);
  stageB(1, 1); ldA(1, Ab);
  __builtin_amdgcn_sched_barrier(0);

  // prologue: reduce 64 cc partial slices, apply mask, write cc tile (swizzled) to scratch
  {
    const int rl = tid >> 2, q = tid & 3;
    const int grow = m0 + rl;
    const int d4 = q * 4;
    float4 ps0 = {0.f, 0.f, 0.f, 0.f}, ps1 = {0.f, 0.f, 0.f, 0.f};
    const float* pp = a.partial + (size_t)dir * 524288 + (size_t)grow * 16 + d4;
#pragma unroll 4
    for (int nb = 0; nb < 64; nb += 2) {
      float4 v0 = *(const float4*)(pp + (size_t)nb * 8192);
      float4 v1 = *(const float4*)(pp + (size_t)(nb + 1) * 8192);
      ps0.x += v0.x; ps0.y += v0.y; ps0.z += v0.z; ps0.w += v0.w;
      ps1.x += v1.x; ps1.y += v1.y; ps1.z += v1.z; ps1.w += v1.w;
    }
    float4 ps = {ps0.x + ps1.x, ps0.y + ps1.y, ps0.z + ps1.z, ps0.w + ps1.w};
    int tt = dir ? (NT - 1 - t) : t;
    float4 x = *(const float4*)(a.values + ((size_t)grow * NT + tt) * ND + d4);
    float4 m = *(const float4*)(a.masks + ((size_t)grow * NT + tt) * ND + d4);
    float4 ob = *(const float4*)(a.outb + d4);
    short4v cc;
    cc[0] = (short)f2bf((1.f - m.x) * (ps.x + ob.x) + m.x * x.x);
    cc[1] = (short)f2bf((1.f - m.y) * (ps.y + ob.y) + m.y * x.y);
    cc[2] = (short)f2bf((1.f - m.z) * (ps.z + ob.z) + m.z * x.z);
    cc[3] = (short)f2bf((1.f - m.w) * (ps.w + ob.w) + m.w * x.w);
    int k2 = rl & 7;
    *(short4v*)(SMX + rl * 64 + (((d4 >> 3) ^ k2) << 3) + (d4 & 7)) = cc;
    short8 z8 = {0, 0, 0, 0, 0, 0, 0, 0};
    *(short8*)(SMX + rl * 64 + (((2 + q) ^ k2) << 3)) = z8;
    if (q < 2) *(short8*)(SMX + rl * 64 + (((6 + q) ^ k2) << 3)) = z8;
    asm volatile("s_waitcnt lgkmcnt(0)" ::: "memory");
    __builtin_amdgcn_sched_barrier(0);
  }

  // chunk 0: A from scratch, B = Wcc (buf0)
  WAITV(8); BARR;
  stageB(2, 2); ldA(2, Ac);
  {
    AF F0;
#pragma unroll
    for (int i = 0; i < 4; ++i) F0.a[i] = *(const short8*)(SMX + aoffs[i]);
    comp(0, F0);
  }
  // chunk 1
  WAITV(8); BARR; stageB(3, 0); ldA(3, Aa); comp(1, Ab);
  // chunks 2..13
  for (int c = 2; c < 14; c += 3) {
    WAITV(8); BARR; stageB(c + 2, 1); ldA(c + 2, Ab); comp(2, Ac);
    WAITV(8); BARR; stageB(c + 3, 2); ldA(c + 3, Ac); comp(0, Aa);
    WAITV(8); BARR; stageB(c + 4, 0); ldA(c + 4, Aa); comp(1, Ab);
  }
  // chunk 14 (pf 16), 15, 16
  WAITV(8); BARR; stageB(16, 1); ldA(16, Ab); comp(2, Ac);
  WAITV(8); BARR; comp(0, Aa);
  WAITV(0); BARR; comp(1, Ab);

  const int hg = ((n0 + wn * 64) >> 2) + fr;
  const float b0 = bias0[n0 + wn * 64 + fr];
  const float b1 = bias0[n0 + wn * 64 + 16 + fr];
  const float b2 = bias0[n0 + wn * 64 + 32 + fr];
  const float b3 = bias0[n0 + wn * 64 + 48 + fr];
#pragma unroll
  for (int mi = 0; mi < 2; ++mi)
#pragma unroll
    for (int r = 0; r < 4; ++r) {
      int row = m0 + wm * 32 + mi * 16 + fq * 4 + r;
      size_t sidx = (size_t)row * NH + hg;
      float iv = acc[mi][0][r] + b0;
      float fv = acc[mi][1][r] + b1;
      float gv = acc[mi][2][r] + b2;
      float ov = acc[mi][3][r] + b3;
      float cp = cs0[sidx];
      float c2 = sigf(fv) * cp + sigf(iv) * tanhf(gv);
      float hvv = sigf(ov) * tanhf(c2);
      cs0[sidx] = c2;
      h0_out[(size_t)row * NH + swz(row, hg)] = f2bf(hvv);
    }
}

// ================= g1: gates = h0@Wih1^T + h1@Whh1^T ; cell + cc-partial =================
__global__ __launch_bounds__(256, 2) void k_g1(StepCtx a, int t) {
  __shared__ u16 SM[3 * 8192];
  const int dir = blockIdx.z, m_blk = blockIdx.y, n_blk = blockIdx.x;
  const int p = t & 1;
  const int m0 = m_blk * 64, n0 = n_blk * 128;
  const int tid = threadIdx.x, w = tid >> 6, lane = tid & 63;
  const int srow = lane >> 3, scol = (lane & 7) * 8;
  const int wm = w >> 1, wn = w & 1;
  const int fr = lane & 15, fq = lane >> 4, key = fr & 7;
  const u16* h0_new = a.h0bf + (size_t)(dir * 2 + 1 - p) * 524288;
  const u16* h1_in = a.h1bf + (size_t)(dir * 2 + p) * 524288;
  u16* h1_out = a.h1bf + (size_t)(dir * 2 + 1 - p) * 524288;
  const u16* W10 = a.wbig + (size_t)(dir * 3 + 1) * 4194304;
  const u16* W11 = a.wbig + (size_t)(dir * 3 + 2) * 4194304;
  const float* bias1 = a.biasb + (size_t)(dir * 2 + 1) * 4096;
  float* cs1 = a.c1 + (size_t)dir * 524288;
  const u16* hA0 = h0_new + (size_t)m0 * NH;
  const u16* hA1 = h1_in + (size_t)m0 * NH;

  int aoffg[4], boff[8];
#pragma unroll
  for (int mi = 0; mi < 2; ++mi)
#pragma unroll
    for (int kk = 0; kk < 2; ++kk)
      aoffg[mi * 2 + kk] = (wm * 32 + mi * 16 + fr) * NH + ((fq + kk * 4) ^ key) * 8;
#pragma unroll
  for (int ni = 0; ni < 4; ++ni)
#pragma unroll
    for (int kk = 0; kk < 2; ++kk)
      boff[ni * 2 + kk] = (wn * 64 + ni * 16 + fr) * 64 + ((fq + kk * 4) ^ key) * 8;

  f32x4 acc[2][4];
#pragma unroll
  for (int i = 0; i < 2; ++i)
#pragma unroll
    for (int j = 0; j < 4; ++j) acc[i][j] = f32x4{0.f, 0.f, 0.f, 0.f};

  auto stageB = [&](int c, int buf) {
    u16* lb = SM + buf * 8192;
    const u16* pw = (c < 16) ? (W10 + (size_t)c * 64) : (W11 + (size_t)(c - 16) * 64);
#pragma unroll
    for (int k = 0; k < 4; ++k)
      glds16(pw + (size_t)(n0 + w * 32 + k * 8 + srow) * NH + scol, lb + (w * 32 + k * 8) * 64);
  };
  auto ldA = [&](int c, AF& F) {
    const u16* pa = (c < 16) ? (hA0 + (size_t)c * 64) : (hA1 + (size_t)(c - 16) * 64);
#pragma unroll
    for (int i = 0; i < 4; ++i) F.a[i] = *(const short8*)(pa + aoffg[i]);
  };
  auto comp = [&](int buf, const AF& F) {
    const u16* base = SM + buf * 8192;
#pragma unroll
    for (int ni = 0; ni < 4; ++ni)
#pragma unroll
      for (int kk = 0; kk < 2; ++kk) {
        short8 bfrag = *(const short8*)(base + boff[ni * 2 + kk]);
#pragma unroll
        for (int mi = 0; mi < 2; ++mi)
          acc[mi][ni] = __builtin_amdgcn_mfma_f32_16x16x32_bf16(F.a[mi * 2 + kk], bfrag, acc[mi][ni], 0, 0, 0);
      }
  };

  AF Aa, Ab, Ac;
  stageB(0, 0); ldA(0, Aa);
  stageB(1, 1); ldA(1, Ab);
  __builtin_amdgcn_sched_barrier(0);

  for (int c = 0; c < 30; c += 3) {
    WAITV(8); BARR; stageB(c + 2, 2); ldA(c + 2, Ac); comp(0, Aa);
    WAITV(8); BARR; stageB(c + 3, 0); ldA(c + 3, Aa); comp(1, Ab);
    WAITV(8); BARR; stageB(c + 4, 1); ldA(c + 4, Ab); comp(2, Ac);
  }
  WAITV(8); BARR; comp(0, Aa);   // chunk 30
  WAITV(0); BARR; comp(1, Ab);   // chunk 31

  const int hb4 = (n0 + wn * 64) >> 2;
  const int hg = hb4 + fr;
  const float b0 = bias1[n0 + wn * 64 + fr];
  const float b1 = bias1[n0 + wn * 64 + 16 + fr];
  const float b2 = bias1[n0 + wn * 64 + 32 + fr];
  const float b3 = bias1[n0 + wn * 64 + 48 + fr];
  float hsv[2][4];
#pragma unroll
  for (int mi = 0; mi < 2; ++mi)
#pragma unroll
    for (int r = 0; r < 4; ++r) {
      int row = m0 + wm * 32 + mi * 16 + fq * 4 + r;
      size_t sidx = (size_t)row * NH + hg;
      float iv = acc[mi][0][r] + b0;
      float fv = acc[mi][1][r] + b1;
      float gv = acc[mi][2][r] + b2;
      float ov = acc[mi][3][r] + b3;
      float cp = cs1[sidx];
      float c2 = sigf(fv) * cp + sigf(iv) * tanhf(gv);
      float hvv = sigf(ov) * tanhf(c2);
      cs1[sidx] = c2;
      h1_out[(size_t)row * NH + swz(row, hg)] = f2bf(hvv);
      hsv[mi][r] = hvv;
    }

  // partial cc = h1_tile @ outW^T via transpose-MFMA; per (n_blk, wn) slice
  {
    u16* ts = SM + w * 512;  // per-wave 16x32 scratch (all pipeline reads retired)
    *(short4v*)(ts + (lane >> 2) * 32 + 16 + (lane & 3) * 4) = short4v{0, 0, 0, 0};
    short8 afr = {0, 0, 0, 0, 0, 0, 0, 0};
    if (fq < 2) afr = *(const short8*)(a.owbf + (size_t)fr * NH + hb4 + fq * 8);
    float* pout = a.partial + ((size_t)(dir * 64 + n_blk * 2 + wn) * 512) * 16;
#pragma unroll
    for (int mi = 0; mi < 2; ++mi) {
#pragma unroll
      for (int r = 0; r < 4; ++r)
        *(ts + (fq * 4 + r) * 32 + fr) = f2bf(hsv[mi][r]);
      asm volatile("s_waitcnt lgkmcnt(0)" ::: "memory");
      __builtin_amdgcn_sched_barrier(0);
      short8 bfr2 = *(const short8*)(ts + fr * 32 + fq * 8);
      f32x4 pz = {0.f, 0.f, 0.f, 0.f};
      pz = __builtin_amdgcn_mfma_f32_16x16x32_bf16(afr, bfr2, pz, 0, 0, 0);
      int row = m0 + wm * 32 + mi * 16 + fr;
      float4 st = {pz[0], pz[1], pz[2], pz[3]};
      *(float4*)(pout + (size_t)row * 16 + fq * 4) = st;
      asm volatile("s_waitcnt lgkmcnt(0)" ::: "memory");
      __builtin_amdgcn_sched_barrier(0);
    }
  }
}

// ---------------- final outputs ----------------
__global__ void k_final(const u16* hf1, const u16* hb1, const float* values,
                        const float* masks, float* out) {
  int idx = blockIdx.x * 256 + threadIdx.x;
  int b = idx >> 10, j = idx & 1023;
  float hf = bf2f(hf1[(size_t)b * NH + swz(b, j)]);
  int jr = NH - 1 - j;
  float hb = bf2f(hb1[(size_t)b * NH + swz(b, jr)]);
  float hv = 0.5f * (hf + hb);
  float m = masks[idx];
  out[idx] = hv;
  out[524288 + idx] = hv;
  out[1048576 + idx] = hv * (1.f - m) + values[idx] * m;
}

extern "C" void kernel_launch(void* const* d_in, const int* in_sizes, int n_in,
                              void* d_out, int out_size, void* d_ws, size_t ws_size,
                              hipStream_t stream) {
  const float* values  = (const float*)d_in[0];
  const float* masks   = (const float*)d_in[1];
  const float* fw_Wih0 = (const float*)d_in[2];
  const float* fw_Whh0 = (const float*)d_in[3];
  const float* fw_bih0 = (const float*)d_in[4];
  const float* fw_bhh0 = (const float*)d_in[5];
  const float* fw_Wih1 = (const float*)d_in[6];
  const float* fw_Whh1 = (const float*)d_in[7];
  const float* fw_bih1 = (const float*)d_in[8];
  const float* fw_bhh1 = (const float*)d_in[9];
  const float* bw_Wih0 = (const float*)d_in[10];
  const float* bw_Whh0 = (const float*)d_in[11];
  const float* bw_bih0 = (const float*)d_in[12];
  const float* bw_bhh0 = (const float*)d_in[13];
  const float* bw_Wih1 = (const float*)d_in[14];
  const float* bw_Whh1 = (const float*)d_in[15];
  const float* bw_bih1 = (const float*)d_in[16];
  const float* bw_bhh1 = (const float*)d_in[17];
  const float* out_W   = (const float*)d_in[18];
  const float* out_b   = (const float*)d_in[19];

  char* ws = (char*)d_ws;
  u16* wbig    = (u16*)ws;                    // 6 x 4M u16 (row-swizzled)
  u16* wih0p   = (u16*)(ws + 50331648);       // 2 x 4096x64 (row-swizzled, K padded)
  float* biasb = (float*)(ws + 51380224);     // 4 x 4096
  u16* owbf    = (u16*)(ws + 51445760);       // 16x1024 bf16
  float* c0    = (float*)(ws + 51478528);     // 2 x 512x1024 f32
  float* c1    = (float*)(ws + 55672832);
  u16* h0bf    = (u16*)(ws + 59867136);       // [dir][pp] x 512x1024 bf16 swizzled
  u16* h1bf    = (u16*)(ws + 64061440);
  float* partial = (float*)(ws + 68255744);   // [dir][64][512][16] f32 = 4 MB
  if (ws_size < 72450048) return;

  k_prep_big<<<4096, 256, 0, stream>>>(fw_Whh0, fw_Wih1, fw_Whh1, bw_Whh0, bw_Wih1, bw_Whh1, wbig);
  k_prep_small<<<2176, 256, 0, stream>>>(fw_Wih0, bw_Wih0, fw_bih0, fw_bhh0, fw_bih1, fw_bhh1,
                                         bw_bih0, bw_bhh0, bw_bih1, bw_bhh1, out_W,
                                         wih0p, biasb, owbf);
  k_init<<<4096, 256, 0, stream>>>(fw_bih1, fw_bhh1, bw_bih1, bw_bhh1, c0, c1, h0bf, h1bf);
  hipMemsetAsync(partial, 0, 4194304, stream);
  k_cc0<<<dim3(128, 2), 256, 0, stream>>>(h1bf, h1bf + (size_t)2 * 524288, out_W, partial);

  StepCtx sc;
  sc.h0bf = h0bf; sc.h1bf = h1bf;
  sc.wbig = wbig; sc.wih0p = wih0p;
  sc.biasb = biasb; sc.c0 = c0; sc.c1 = c1;
  sc.partial = partial;
  sc.values = values; sc.masks = masks; sc.outb = out_b;
  sc.owbf = owbf;

  for (int t = 0; t < NT; ++t) {
    k_g0<<<dim3(32, 8, 2), 256, 0, stream>>>(sc, t);
    k_g1<<<dim3(32, 8, 2), 256, 0, stream>>>(sc, t);
  }

  // after t=63: p=1, final h1 in buffer (1-p)=0
  k_final<<<2048, 256, 0, stream>>>(h1bf, h1bf + (size_t)2 * 524288, values, masks, (float*)d_out);
}